// Round 1
// baseline (375.415 us; speedup 1.0000x reference)
//
#include <hip/hip_runtime.h>
#include <hip/hip_bf16.h>
#include <math.h>

// B=2, S=4096, H=512, NH=8, HD=64. M = B*S = 8192.
// All heavy compute in bf16 MFMA (16x16x32), fp32 accumulate.

typedef __bf16 bf16;
typedef __bf16 bf16x4 __attribute__((ext_vector_type(4)));
typedef __bf16 bf16x8 __attribute__((ext_vector_type(8)));
typedef float  f32x4  __attribute__((ext_vector_type(4)));

#define MFMA16(a, b, c) __builtin_amdgcn_mfma_f32_16x16x32_bf16((a), (b), (c), 0, 0, 0)

// ---------------- fp32 -> bf16 convert ----------------
__global__ __launch_bounds__(256) void cvt_f32_bf16(const float* __restrict__ src,
                                                    bf16* __restrict__ dst, int n) {
    int i = (blockIdx.x * 256 + threadIdx.x) * 4;
    if (i >= n) return;
    float4 v = *reinterpret_cast<const float4*>(src + i);
    bf16x4 o = {(bf16)v.x, (bf16)v.y, (bf16)v.z, (bf16)v.w};
    *reinterpret_cast<bf16x4*>(dst + i) = o;
}

// ---------------- GEMM: C = A[M,K] * W[N,K]^T + bias ----------------
// MODE 0: QKV projection. grid.z in {0,1,2} selects (Wq,bq)->Q, (Wk,bk)->K, (Wv,bv)->V.
//         Output bf16, head-split layout [B][NH][S][HD]. Q gets *0.125 (1/sqrt(HD)) folded in.
// MODE 1: output projection. fp32 output [M][512].
// Tile: BM=BN=128, BK=64. 256 threads = 4 waves, each wave does 64x64 (4x4 16x16 frags).
template <int MODE>
__global__ __launch_bounds__(256) void gemm_bt(const bf16* __restrict__ A,
                                               const bf16* __restrict__ W,
                                               const float* __restrict__ b0,
                                               const float* __restrict__ b1,
                                               const float* __restrict__ b2,
                                               bf16* __restrict__ dstbf,
                                               float* __restrict__ dstf) {
    __shared__ bf16 sA[128][72];  // +8 pad: 144B row stride -> 2-way (free) bank aliasing
    __shared__ bf16 sB[128][72];

    const int tid = threadIdx.x;
    const int w   = tid >> 6;
    const int l   = tid & 63;
    const int m0  = blockIdx.y * 128;
    const int n0  = blockIdx.x * 128;
    const int z   = blockIdx.z;

    const bf16*  Wz   = (MODE == 0) ? (W + z * 262144) : W;
    const float* bias = (MODE == 0) ? (z == 0 ? b0 : (z == 1 ? b1 : b2)) : b0;
    const float  scale = (MODE == 0 && z == 0) ? 0.125f : 1.0f;

    const int wr = (w >> 1) * 64, wc = (w & 1) * 64;
    const int fr = l & 15, fg = l >> 4;

    f32x4 acc[4][4];
    const f32x4 zero = {0.f, 0.f, 0.f, 0.f};
#pragma unroll
    for (int i = 0; i < 4; i++)
#pragma unroll
        for (int j = 0; j < 4; j++) acc[i][j] = zero;

    for (int kt = 0; kt < 512; kt += 64) {
        __syncthreads();
        // stage A and W tiles (reg-staged, coalesced 16B/lane)
#pragma unroll
        for (int i = 0; i < 4; i++) {
            int c = i * 256 + tid;      // 0..1023
            int row = c >> 3, col = (c & 7) * 8;
            bf16x8 va = *reinterpret_cast<const bf16x8*>(A  + (m0 + row) * 512 + kt + col);
            *reinterpret_cast<bf16x8*>(&sA[row][col]) = va;
            bf16x8 vb = *reinterpret_cast<const bf16x8*>(Wz + (n0 + row) * 512 + kt + col);
            *reinterpret_cast<bf16x8*>(&sB[row][col]) = vb;
        }
        __syncthreads();

#pragma unroll
        for (int kk = 0; kk < 64; kk += 32) {
            bf16x8 af[4], bfg[4];
#pragma unroll
            for (int mi = 0; mi < 4; mi++)
                af[mi] = *reinterpret_cast<const bf16x8*>(&sA[wr + mi * 16 + fr][kk + fg * 8]);
#pragma unroll
            for (int ni = 0; ni < 4; ni++)
                bfg[ni] = *reinterpret_cast<const bf16x8*>(&sB[wc + ni * 16 + fr][kk + fg * 8]);
#pragma unroll
            for (int mi = 0; mi < 4; mi++)
#pragma unroll
                for (int ni = 0; ni < 4; ni++)
                    acc[mi][ni] = MFMA16(af[mi], bfg[ni], acc[mi][ni]);
        }
    }

    // epilogue. C/D layout: lane holds col = (l&15), rows = (l>>4)*4 + r
#pragma unroll
    for (int mi = 0; mi < 4; mi++) {
#pragma unroll
        for (int ni = 0; ni < 4; ni++) {
            const int gcol = n0 + wc + ni * 16 + fr;
            const float bc = bias[gcol];
#pragma unroll
            for (int r = 0; r < 4; r++) {
                const int grow = m0 + wr + mi * 16 + fg * 4 + r;
                float v = acc[mi][ni][r] + bc;
                if (MODE == 0) {
                    v *= scale;
                    const int bb = grow >> 12, s = grow & 4095;
                    const int hh = gcol >> 6, dd = gcol & 63;
                    dstbf[z * 4194304 + ((((bb * 8 + hh) * 4096) + s) << 6) + dd] = (bf16)v;
                } else {
                    dstf[grow * 512 + gcol] = v;
                }
            }
        }
    }
}

// ---------------- Flash attention ----------------
// grid: (S/64, B*NH). 256 threads = 4 waves; wave w owns q rows [q0+16w, q0+16w+16).
// KV tile = 64. Q,K,V are bf16 [B][NH][S][HD]; Q pre-scaled by 1/sqrt(HD).
__global__ __launch_bounds__(256) void attn_kernel(const bf16* __restrict__ Q,
                                                   const bf16* __restrict__ K,
                                                   const bf16* __restrict__ V,
                                                   bf16* __restrict__ ctx) {
    __shared__ bf16 sK[64][72];       // [kv][d], padded
    __shared__ bf16 sV[64][72];       // transposed: [d][kv], padded
    __shared__ bf16 sP[4][16][72];    // per-wave P tile [q_local][kv], padded

    const int tid = threadIdx.x;
    const int w   = tid >> 6;
    const int l   = tid & 63;
    const int fr  = l & 15, fg = l >> 4;
    const int bh  = blockIdx.y;
    const int q0  = blockIdx.x * 64;
    const int base = bh * 4096 * 64;

    // Q fragments for this wave's 16 rows (A-operand, K-dim = d)
    bf16x8 qf[2];
    const int qrow = q0 + w * 16 + fr;
#pragma unroll
    for (int ks = 0; ks < 2; ks++)
        qf[ks] = *reinterpret_cast<const bf16x8*>(Q + base + qrow * 64 + ks * 32 + fg * 8);

    f32x4 o[4];
    const f32x4 zero = {0.f, 0.f, 0.f, 0.f};
#pragma unroll
    for (int db = 0; db < 4; db++) o[db] = zero;
    float m[4]    = {-3.0e38f, -3.0e38f, -3.0e38f, -3.0e38f};
    float lsum[4] = {0.f, 0.f, 0.f, 0.f};

    for (int t = 0; t < 4096; t += 64) {
        __syncthreads();
        // stage K tile and V tile (V written transposed)
#pragma unroll
        for (int i = 0; i < 2; i++) {
            int c = i * 256 + tid;     // 0..511
            int row = c >> 3, col = (c & 7) * 8;
            *reinterpret_cast<bf16x8*>(&sK[row][col]) =
                *reinterpret_cast<const bf16x8*>(K + base + (t + row) * 64 + col);
            bf16x8 vv = *reinterpret_cast<const bf16x8*>(V + base + (t + row) * 64 + col);
#pragma unroll
            for (int e = 0; e < 8; e++) sV[col + e][row] = vv[e];
        }
        __syncthreads();

        // S = Q K^T  (C rows = q, cols = kv)
        f32x4 sc[4];
#pragma unroll
        for (int kvb = 0; kvb < 4; kvb++) {
            sc[kvb] = zero;
#pragma unroll
            for (int ks = 0; ks < 2; ks++) {
                bf16x8 kf = *reinterpret_cast<const bf16x8*>(&sK[kvb * 16 + fr][ks * 32 + fg * 8]);
                sc[kvb] = MFMA16(qf[ks], kf, sc[kvb]);
            }
        }

        // online softmax: rows live across the 16 lanes sharing fg
#pragma unroll
        for (int r = 0; r < 4; r++) {
            float mx = fmaxf(fmaxf(sc[0][r], sc[1][r]), fmaxf(sc[2][r], sc[3][r]));
            mx = fmaxf(mx, __shfl_xor(mx, 1));
            mx = fmaxf(mx, __shfl_xor(mx, 2));
            mx = fmaxf(mx, __shfl_xor(mx, 4));
            mx = fmaxf(mx, __shfl_xor(mx, 8));
            const float newm = fmaxf(m[r], mx);
            const float rescale = __expf(m[r] - newm);   // m starts at -3e38 -> exp = 0
            float rs = 0.f;
#pragma unroll
            for (int kvb = 0; kvb < 4; kvb++) {
                float p = __expf(sc[kvb][r] - newm);
                sc[kvb][r] = p;
                rs += p;
            }
            rs += __shfl_xor(rs, 1);
            rs += __shfl_xor(rs, 2);
            rs += __shfl_xor(rs, 4);
            rs += __shfl_xor(rs, 8);
            lsum[r] = lsum[r] * rescale + rs;
            m[r] = newm;
#pragma unroll
            for (int db = 0; db < 4; db++) o[db][r] *= rescale;
        }

        // P -> LDS (bf16), per-wave private region; same-wave DS ordering is in-order
#pragma unroll
        for (int kvb = 0; kvb < 4; kvb++)
#pragma unroll
            for (int r = 0; r < 4; r++)
                sP[w][fg * 4 + r][kvb * 16 + fr] = (bf16)sc[kvb][r];

        // O += P V   (A = P[q][kv], B = V[kv][d] read from transposed sV)
#pragma unroll
        for (int ks = 0; ks < 2; ks++) {
            bf16x8 pf = *reinterpret_cast<const bf16x8*>(&sP[w][fr][ks * 32 + fg * 8]);
#pragma unroll
            for (int db = 0; db < 4; db++) {
                bf16x8 vf = *reinterpret_cast<const bf16x8*>(&sV[db * 16 + fr][ks * 32 + fg * 8]);
                o[db] = MFMA16(pf, vf, o[db]);
            }
        }
    }

    // epilogue: ctx[b][s][h*64+d], bf16
    const int bb = bh >> 3, hh = bh & 7;
#pragma unroll
    for (int r = 0; r < 4; r++) {
        const float inv = 1.0f / lsum[r];
        const int s = q0 + w * 16 + fg * 4 + r;
#pragma unroll
        for (int db = 0; db < 4; db++)
            ctx[((size_t)(bb * 4096 + s)) * 512 + hh * 64 + db * 16 + fr] = (bf16)(o[db][r] * inv);
    }
}

// ---------------- launch ----------------
extern "C" void kernel_launch(void* const* d_in, const int* in_sizes, int n_in,
                              void* d_out, int out_size, void* d_ws, size_t ws_size,
                              hipStream_t stream) {
    const float* X  = (const float*)d_in[0];
    const float* Wq = (const float*)d_in[1];
    const float* bq = (const float*)d_in[2];
    const float* Wk = (const float*)d_in[3];
    const float* bk = (const float*)d_in[4];
    const float* Wv = (const float*)d_in[5];
    const float* bv = (const float*)d_in[6];
    const float* Wo = (const float*)d_in[7];
    const float* bo = (const float*)d_in[8];
    float* out = (float*)d_out;

    bf16* ws  = (bf16*)d_ws;
    bf16* Xbf = ws;                    // 4,194,304
    bf16* Wqb = Xbf + 4194304;         // 262,144
    bf16* Wkb = Wqb + 262144;
    bf16* Wvb = Wkb + 262144;
    bf16* Wob = Wvb + 262144;
    bf16* Qb  = Wob + 262144;          // 4,194,304 each, Q/K/V contiguous
    bf16* Kb  = Qb + 4194304;
    bf16* Vb  = Kb + 4194304;
    bf16* Ctx = Vb + 4194304;

    cvt_f32_bf16<<<4096, 256, 0, stream>>>(X, Xbf, 4194304);
    cvt_f32_bf16<<<256, 256, 0, stream>>>(Wq, Wqb, 262144);
    cvt_f32_bf16<<<256, 256, 0, stream>>>(Wk, Wkb, 262144);
    cvt_f32_bf16<<<256, 256, 0, stream>>>(Wv, Wvb, 262144);
    cvt_f32_bf16<<<256, 256, 0, stream>>>(Wo, Wob, 262144);

    // QKV projections (Q scaled by 0.125), head-split bf16 outputs
    gemm_bt<0><<<dim3(4, 64, 3), 256, 0, stream>>>(Xbf, Wqb, bq, bk, bv, Qb, nullptr);

    // flash attention -> ctx bf16 [B][S][H]
    attn_kernel<<<dim3(64, 16), 256, 0, stream>>>(Qb, Kb, Vb, Ctx);

    // output projection -> fp32 d_out
    gemm_bt<1><<<dim3(4, 64, 1), 256, 0, stream>>>(Ctx, Wob, bo, nullptr, nullptr, nullptr, out);
}

// Round 2
// 203.209 us; speedup vs baseline: 1.8474x; 1.8474x over previous
//
#include <hip/hip_runtime.h>
#include <hip/hip_bf16.h>
#include <math.h>

// B=2, S=4096, H=512, NH=8, HD=64. M = B*S = 8192.
// All heavy compute in bf16 MFMA (16x16x32), fp32 accumulate.

typedef __bf16 bf16;
typedef __bf16 bf16x2v __attribute__((ext_vector_type(2)));
typedef __bf16 bf16x4 __attribute__((ext_vector_type(4)));
typedef __bf16 bf16x8 __attribute__((ext_vector_type(8)));
typedef float  f32x4  __attribute__((ext_vector_type(4)));

#define MFMA16(a, b, c) __builtin_amdgcn_mfma_f32_16x16x32_bf16((a), (b), (c), 0, 0, 0)

// ---------------- fp32 -> bf16 convert ----------------
__global__ __launch_bounds__(256) void cvt_f32_bf16(const float* __restrict__ src,
                                                    bf16* __restrict__ dst, int n) {
    int i = (blockIdx.x * 256 + threadIdx.x) * 4;
    if (i >= n) return;
    float4 v = *reinterpret_cast<const float4*>(src + i);
    bf16x4 o = {(bf16)v.x, (bf16)v.y, (bf16)v.z, (bf16)v.w};
    *reinterpret_cast<bf16x4*>(dst + i) = o;
}

// ---------------- GEMM: C = A[M,K] * W[N,K]^T + bias ----------------
// MODE 0: QKV projection. z in {0,1,2}: Q (scaled 0.125, head-split), K (head-split),
//         V (written TRANSPOSED per head: Vt[bh][d][s]).
// MODE 1: output projection. fp32 output [M][512].
template <int MODE>
__global__ __launch_bounds__(256) void gemm_bt(const bf16* __restrict__ A,
                                               const bf16* __restrict__ W,
                                               const float* __restrict__ b0,
                                               const float* __restrict__ b1,
                                               const float* __restrict__ b2,
                                               bf16* __restrict__ dstbf,
                                               float* __restrict__ dstf) {
    __shared__ bf16 sA[128][72];
    __shared__ bf16 sB[128][72];

    const int tid = threadIdx.x;
    const int w   = tid >> 6;
    const int l   = tid & 63;
    const int m0  = blockIdx.y * 128;
    const int n0  = blockIdx.x * 128;
    const int z   = blockIdx.z;

    const bf16*  Wz   = (MODE == 0) ? (W + z * 262144) : W;
    const float* bias = (MODE == 0) ? (z == 0 ? b0 : (z == 1 ? b1 : b2)) : b0;
    const float  scale = (MODE == 0 && z == 0) ? 0.125f : 1.0f;

    const int wr = (w >> 1) * 64, wc = (w & 1) * 64;
    const int fr = l & 15, fg = l >> 4;

    f32x4 acc[4][4];
    const f32x4 zero = {0.f, 0.f, 0.f, 0.f};
#pragma unroll
    for (int i = 0; i < 4; i++)
#pragma unroll
        for (int j = 0; j < 4; j++) acc[i][j] = zero;

    for (int kt = 0; kt < 512; kt += 64) {
        __syncthreads();
#pragma unroll
        for (int i = 0; i < 4; i++) {
            int c = i * 256 + tid;
            int row = c >> 3, col = (c & 7) * 8;
            bf16x8 va = *reinterpret_cast<const bf16x8*>(A  + (m0 + row) * 512 + kt + col);
            *reinterpret_cast<bf16x8*>(&sA[row][col]) = va;
            bf16x8 vb = *reinterpret_cast<const bf16x8*>(Wz + (n0 + row) * 512 + kt + col);
            *reinterpret_cast<bf16x8*>(&sB[row][col]) = vb;
        }
        __syncthreads();

#pragma unroll
        for (int kk = 0; kk < 64; kk += 32) {
            bf16x8 af[4], bfg[4];
#pragma unroll
            for (int mi = 0; mi < 4; mi++)
                af[mi] = *reinterpret_cast<const bf16x8*>(&sA[wr + mi * 16 + fr][kk + fg * 8]);
#pragma unroll
            for (int ni = 0; ni < 4; ni++)
                bfg[ni] = *reinterpret_cast<const bf16x8*>(&sB[wc + ni * 16 + fr][kk + fg * 8]);
#pragma unroll
            for (int mi = 0; mi < 4; mi++)
#pragma unroll
                for (int ni = 0; ni < 4; ni++)
                    acc[mi][ni] = MFMA16(af[mi], bfg[ni], acc[mi][ni]);
        }
    }

#pragma unroll
    for (int mi = 0; mi < 4; mi++) {
#pragma unroll
        for (int ni = 0; ni < 4; ni++) {
            const int gcol = n0 + wc + ni * 16 + fr;
            const float bc = bias[gcol];
#pragma unroll
            for (int r = 0; r < 4; r++) {
                const int grow = m0 + wr + mi * 16 + fg * 4 + r;
                float v = acc[mi][ni][r] + bc;
                if (MODE == 0) {
                    v *= scale;
                    const int bb = grow >> 12, s = grow & 4095;
                    const int hh = gcol >> 6, dd = gcol & 63;
                    size_t idx;
                    if (z == 2) {
                        // V^T per head: Vt[bh][d][s]
                        idx = (size_t)2 * 4194304 +
                              ((size_t)((bb * 8 + hh) * 64 + dd)) * 4096 + s;
                    } else {
                        idx = (size_t)z * 4194304 +
                              ((size_t)((bb * 8 + hh) * 4096 + s) << 6) + dd;
                    }
                    dstbf[idx] = (bf16)v;
                } else {
                    dstf[grow * 512 + gcol] = v;
                }
            }
        }
    }
}

// ---------------- Flash attention (swapped QK^T, swizzled LDS) ----------------
// grid: (S/64, B*NH). 256 threads = 4 waves; wave w owns q rows [q0+16w, q0+16w+16).
// K: [bh][s][64], Vt: [bh][d][4096]. Q pre-scaled by 1/sqrt(HD).
__global__ __launch_bounds__(256) void attn_kernel(const bf16* __restrict__ Q,
                                                   const bf16* __restrict__ K,
                                                   const bf16* __restrict__ Vt,
                                                   bf16* __restrict__ ctx) {
    __shared__ bf16 sK[64 * 64];      // [kv][d], XOR-swizzled 16B granules
    __shared__ bf16 sV[64 * 64];      // [d][kv], XOR-swizzled 16B granules
    __shared__ bf16 sP[4][16][72];    // per-wave P tile [q=fr][kv], padded

    const int tid = threadIdx.x;
    const int w   = tid >> 6;
    const int l   = tid & 63;
    const int fr  = l & 15, fg = l >> 4;
    const int bh  = blockIdx.y;
    const int q0  = blockIdx.x * 64;
    const size_t base = (size_t)bh * 262144;   // 4096*64

    // staging geometry: wave w stages rows [16w,16w+16) in 2 passes of 8 rows.
    const int srow = (w << 4) + (l >> 3);      // row for pass 0 (pass 1: +8)
    const int sgr  = (l & 7) ^ (l >> 3);       // pre-swizzled source granule
    const int lco  = (l & 7) * 8;              // linear LDS col (elems)

    // Q fragments (B-operand: col=q=fr, k=d)
    bf16x8 qf[2];
    const int qrow = q0 + (w << 4) + fr;
#pragma unroll
    for (int ks = 0; ks < 2; ks++)
        qf[ks] = *reinterpret_cast<const bf16x8*>(Q + base + (size_t)qrow * 64 + ks * 32 + fg * 8);

    const f32x4 zero = {0.f, 0.f, 0.f, 0.f};
    f32x4 o[4];
#pragma unroll
    for (int db = 0; db < 4; db++) o[db] = zero;
    float m = -3.0e38f, lsum = 0.f;

    // prologue prefetch (tile t=0)
    bf16x8 kreg[2], vreg[2];
#pragma unroll
    for (int q = 0; q < 2; q++) {
        const int row = srow + 8 * q;
        kreg[q] = *reinterpret_cast<const bf16x8*>(K  + base + (size_t)row * 64 + sgr * 8);
        vreg[q] = *reinterpret_cast<const bf16x8*>(Vt + base + (size_t)row * 4096 + sgr * 8);
    }

    for (int t = 0; t < 4096; t += 64) {
        __syncthreads();   // all waves done reading previous tiles
#pragma unroll
        for (int q = 0; q < 2; q++) {
            const int row = srow + 8 * q;
            *reinterpret_cast<bf16x8*>(sK + row * 64 + lco) = kreg[q];
            *reinterpret_cast<bf16x8*>(sV + row * 64 + lco) = vreg[q];
        }
        __syncthreads();   // tiles ready

        if (t + 64 < 4096) {
#pragma unroll
            for (int q = 0; q < 2; q++) {
                const int row = srow + 8 * q;
                kreg[q] = *reinterpret_cast<const bf16x8*>(K  + base + (size_t)(t + 64 + row) * 64 + sgr * 8);
                vreg[q] = *reinterpret_cast<const bf16x8*>(Vt + base + (size_t)row * 4096 + (t + 64) + sgr * 8);
            }
        }

        // --- QK^T swapped: sc[kvb][r] = S[kv=16kvb+4fg+r][q=fr] ---
        f32x4 sc[4];
#pragma unroll
        for (int kvb = 0; kvb < 4; kvb++) {
            sc[kvb] = zero;
#pragma unroll
            for (int ks = 0; ks < 2; ks++) {
                const bf16x8 kf = *reinterpret_cast<const bf16x8*>(
                    sK + (16 * kvb + fr) * 64 + (((4 * ks + fg) ^ (fr & 7)) << 3));
                sc[kvb] = MFMA16(kf, qf[ks], sc[kvb]);
            }
        }

        // --- per-lane online softmax (lane owns full kv-row subset for q=fr) ---
        float mx = fmaxf(fmaxf(sc[0][0], sc[0][1]), fmaxf(sc[0][2], sc[0][3]));
#pragma unroll
        for (int kvb = 1; kvb < 4; kvb++)
            mx = fmaxf(mx, fmaxf(fmaxf(sc[kvb][0], sc[kvb][1]), fmaxf(sc[kvb][2], sc[kvb][3])));
        mx = fmaxf(mx, __shfl_xor(mx, 16));
        mx = fmaxf(mx, __shfl_xor(mx, 32));
        const float newm = fmaxf(m, mx);
        const float resc = __expf(m - newm);
        float rs = 0.f;
#pragma unroll
        for (int kvb = 0; kvb < 4; kvb++) {
#pragma unroll
            for (int r = 0; r < 4; r++) {
                const float p = __expf(sc[kvb][r] - newm);
                sc[kvb][r] = p;
                rs += p;
            }
        }
        rs += __shfl_xor(rs, 16);
        rs += __shfl_xor(rs, 32);
        lsum = lsum * resc + rs;
        m = newm;

        // rescale O (rows q_local = 4fg+r; stats live on lane fr'=4fg+r)
#pragma unroll
        for (int r = 0; r < 4; r++) {
            const float f = __shfl(resc, 4 * fg + r);
            o[0][r] *= f; o[1][r] *= f; o[2][r] *= f; o[3][r] *= f;
        }

        // --- P -> sP (packed b32 writes) ---
#pragma unroll
        for (int kvb = 0; kvb < 4; kvb++) {
#pragma unroll
            for (int t2 = 0; t2 < 2; t2++) {
                bf16x2v pp = {(bf16)sc[kvb][2 * t2], (bf16)sc[kvb][2 * t2 + 1]};
                *reinterpret_cast<bf16x2v*>(&sP[w][fr][16 * kvb + 4 * fg + 2 * t2]) = pp;
            }
        }

        // --- O += P V  (A=P rows q=fr; B=Vt cols d=16db+fr) ---
#pragma unroll
        for (int ks = 0; ks < 2; ks++) {
            const bf16x8 pf = *reinterpret_cast<const bf16x8*>(&sP[w][fr][ks * 32 + fg * 8]);
#pragma unroll
            for (int db = 0; db < 4; db++) {
                const bf16x8 vf = *reinterpret_cast<const bf16x8*>(
                    sV + (16 * db + fr) * 64 + (((4 * ks + fg) ^ (fr & 7)) << 3));
                o[db] = MFMA16(pf, vf, o[db]);
            }
        }
    }

    // epilogue: ctx[b][s][h*64+d]; O rows q_local=4fg+r, cols d=16db+fr
    const int bb = bh >> 3, hh = bh & 7;
#pragma unroll
    for (int r = 0; r < 4; r++) {
        const float ls  = __shfl(lsum, 4 * fg + r);
        const float inv = 1.0f / ls;
        const int s = q0 + (w << 4) + 4 * fg + r;
#pragma unroll
        for (int db = 0; db < 4; db++)
            ctx[((size_t)(bb * 4096 + s)) * 512 + hh * 64 + db * 16 + fr] = (bf16)(o[db][r] * inv);
    }
}

// ---------------- launch ----------------
extern "C" void kernel_launch(void* const* d_in, const int* in_sizes, int n_in,
                              void* d_out, int out_size, void* d_ws, size_t ws_size,
                              hipStream_t stream) {
    const float* X  = (const float*)d_in[0];
    const float* Wq = (const float*)d_in[1];
    const float* bq = (const float*)d_in[2];
    const float* Wk = (const float*)d_in[3];
    const float* bk = (const float*)d_in[4];
    const float* Wv = (const float*)d_in[5];
    const float* bv = (const float*)d_in[6];
    const float* Wo = (const float*)d_in[7];
    const float* bo = (const float*)d_in[8];
    float* out = (float*)d_out;

    bf16* ws  = (bf16*)d_ws;
    bf16* Xbf = ws;                    // 4,194,304
    bf16* Wqb = Xbf + 4194304;         // 262,144
    bf16* Wkb = Wqb + 262144;
    bf16* Wvb = Wkb + 262144;
    bf16* Wob = Wvb + 262144;
    bf16* Qb  = Wob + 262144;          // Q / K / Vt each 4,194,304
    bf16* Kb  = Qb + 4194304;
    bf16* Vtb = Kb + 4194304;
    bf16* Ctx = Vtb + 4194304;

    cvt_f32_bf16<<<4096, 256, 0, stream>>>(X, Xbf, 4194304);
    cvt_f32_bf16<<<256, 256, 0, stream>>>(Wq, Wqb, 262144);
    cvt_f32_bf16<<<256, 256, 0, stream>>>(Wk, Wkb, 262144);
    cvt_f32_bf16<<<256, 256, 0, stream>>>(Wv, Wvb, 262144);
    cvt_f32_bf16<<<256, 256, 0, stream>>>(Wo, Wob, 262144);

    // projections: Q (scaled, head-split), K (head-split), V -> Vt[bh][d][s]
    gemm_bt<0><<<dim3(4, 64, 3), 256, 0, stream>>>(Xbf, Wqb, bq, bk, bv, Qb, nullptr);

    // flash attention -> ctx bf16 [B][S][H]
    attn_kernel<<<dim3(64, 16), 256, 0, stream>>>(Qb, Kb, Vtb, Ctx);

    // output projection -> fp32 d_out
    gemm_bt<1><<<dim3(4, 64, 1), 256, 0, stream>>>(Ctx, Wob, bo, nullptr, nullptr, nullptr, out);
}